// Round 6
// baseline (598.531 us; speedup 1.0000x reference)
//
#include <hip/hip_runtime.h>
#include <stdint.h>
#include <stddef.h>

// Problem constants
#define BSZ 128
#define CIN 32
#define COUT 32
#define HN 4096
#define K7 7
#define NTOT (BSZ*CIN*HN)     // 16,777,216 elements
#define NBH  (BSZ*HN)         // 524,288 (b,h) pairs

typedef __attribute__((ext_vector_type(8))) short short8;
typedef __attribute__((ext_vector_type(4))) float f32x4;

// ws layout (bytes)
#define WS_XT   0            // bf16 xt[B][H][32]            : 33,554,432 B
#define WS_WT   33554432     // bf16 wt[o][kk][c]            : 14,336 B
#define WS_NBR  33568768     // int32 nbr_pack[H][8]         : 131,072 B
#define WS_INVD 33699840     // float invd[H]                : 16,384 B
#define WS_OSTP 33716224     // float ostatp[64][64]         : 16,384 B
#define WS_BAR  33732608     // int bar[1024]                : 4,096 B

__device__ __forceinline__ unsigned short f32_to_bf16(float f){
    union { float f; uint32_t u; } v; v.f = f;
    uint32_t u = v.u;
    return (unsigned short)((u + 0x7FFFu + ((u >> 16) & 1u)) >> 16);
}
__device__ __forceinline__ float bf16_to_f32(unsigned short h){
    union { uint32_t u; float f; } v; v.u = ((uint32_t)h) << 16;
    return v.f;
}

// ---------------------------------------------------------------------------
// kinit: blocks 0..15: neighbor table + invd + zero ostatp + zero barrier.
//        block 16: pack weights (bf16, A-frag order; no std fold, no bias —
//        BatchNorm exactly cancels both).
// NOTE: harness passes integer inputs as int32 (not the reference's int64).
__global__ void kinit(const int* __restrict__ nbr,
                      const float* __restrict__ w,
                      int* __restrict__ nbr_pack,
                      float* __restrict__ invd,
                      unsigned short* __restrict__ wt,
                      float* __restrict__ ostatp,
                      int* __restrict__ bar){
    int t = threadIdx.x;
    if (blockIdx.x < 16){
        int h = blockIdx.x*256 + t;       // 0..4095
        ostatp[h] = 0.0f;                 // 4096 floats = 64x64
        if (h < 1024) bar[h] = 0;         // barrier slots
        int cnt = 0;
        int pk[8];
        #pragma unroll
        for (int j = 0; j < 6; j++){
            int iv = nbr[h*6 + j];
            if (iv >= HN) iv = HN - 1;    // safety clamp (never expected)
            if (iv >= 0) cnt++; else iv = -1;
            pk[j] = iv;
        }
        pk[6] = cnt; pk[7] = 0;
        #pragma unroll
        for (int j = 0; j < 8; j++) nbr_pack[h*8 + j] = pk[j];
        invd[h] = 1.0f / ((float)cnt + 1.0f + 1e-6f);
    } else {
        for (int i = t; i < COUT*K7*CIN; i += 256){
            int o  = i / (K7*CIN);
            int kk = (i / CIN) % K7;
            int c  = i % CIN;
            wt[i] = f32_to_bf16(w[(o*CIN + c)*K7 + kk]);
        }
    }
}

// ---------------------------------------------------------------------------
// ktrans: transpose x[B][C][H] f32 -> xt[B][H][C] bf16.
// grid = 128 b * 16 h-tiles(256h) = 2048 blocks of 256.
__global__ void ktrans(const float* __restrict__ x,
                       unsigned short* __restrict__ xt){
    __shared__ float tile[32][260];
    int b  = blockIdx.x >> 4;
    int h0 = (blockIdx.x & 15) << 8;
    int t  = threadIdx.x;
    #pragma unroll
    for (int l = 0; l < 8; l++){
        int linear = l*256 + t;
        int c  = linear >> 6;
        int h4 = linear & 63;
        float4 v = *(const float4*)(x + ((size_t)(b*CIN + c))*HN + h0 + h4*4);
        *(float4*)&tile[c][h4*4] = v;
    }
    __syncthreads();
    int cg = (t & 3) * 8;
    int hw = t >> 2;                      // 0..63
    #pragma unroll
    for (int r = 0; r < 4; r++){
        int h = r*64 + hw;
        alignas(16) unsigned short tmp[8];
        #pragma unroll
        for (int j = 0; j < 8; j++) tmp[j] = f32_to_bf16(tile[cg + j][h]);
        *(uint4*)(xt + ((size_t)(b*HN + h0 + h))*32 + cg) = *(const uint4*)tmp;
    }
}

// ---------------------------------------------------------------------------
__device__ __forceinline__ void gather7(short8* dst, const unsigned short* xb,
                                        int selfrow, int4 na, int4 nb, int quad){
    const short8 zero8 = {0,0,0,0,0,0,0,0};
    dst[0] = *(const short8*)(xb + (size_t)selfrow*CIN + quad*8);
    int rows[6] = {na.x, na.y, na.z, na.w, nb.x, nb.y};
    #pragma unroll
    for (int k = 0; k < 6; k++){
        int r  = rows[k];
        int rc = r < 0 ? 0 : r;
        dst[k+1] = *(const short8*)(xb + (size_t)rc*CIN + quad*8);
        if (r < 0) dst[k+1] = zero8;
    }
}

// ---------------------------------------------------------------------------
// kfused: ONE conv execution. Phase A: gather+MFMA, park pre-BN values packed
// bf16 in LDS (held[8][256] x 16B). Phase B1: stats from parked values ->
// 64-slot atomics. Grid barrier (1024 blocks all co-resident by construction:
// LB(256,4) => VGPR<=128 => 4 blocks/CU; LDS 34KB <= 40KB/block). Phase B2:
// redundant per-block stat reduction -> BN coefficients. Phase B3: unpark,
// apply BN, write f32 out.
// XCD swizzle: blk&7 -> b-range per XCD, xt gathers stay L2-local (R4-verified).
__global__ __launch_bounds__(256, 4) void kfused(
    const unsigned short* __restrict__ xt,
    const unsigned short* __restrict__ wt,
    const int* __restrict__ nbrp,
    const float* __restrict__ invd,
    const float* __restrict__ gamma,
    const float* __restrict__ beta,
    float* __restrict__ out,
    float* __restrict__ ostatp,
    int* __restrict__ bar)
{
    __shared__ uint4 held[8*256];         // 32 KB: held[it][threadIdx]
    __shared__ float part[4][64];
    __shared__ float scsh[64];

    int t    = threadIdx.x;
    int lane = t & 63;
    int wv   = t >> 6;
    int n    = lane & 15;
    int quad = lane >> 4;
    int xcd  = blockIdx.x & 7;
    int j    = blockIdx.x >> 3;           // 0..127
    int b    = xcd*16 + (j >> 3);         // 16 b per XCD
    int hbase= (j & 7)*512 + wv*128;      // wave: 128 h = 8 tiles of 16

    // A fragments (W): lane holds W[o=n+16mt][ik=kk*32 + quad*8 + jj]
    short8 af[2][K7];
    #pragma unroll
    for (int mt = 0; mt < 2; mt++){
        int o = n + 16*mt;
        #pragma unroll
        for (int kk = 0; kk < K7; kk++)
            af[mt][kk] = *(const short8*)(wt + (size_t)(o*K7 + kk)*CIN + quad*8);
    }

    const unsigned short* xb = xt + (size_t)b*HN*CIN;

    // ---- Phase A: conv, park packed bf16 in LDS ----
    #pragma unroll 2
    for (int it = 0; it < 8; it++){
        int hc = hbase + it*16 + n;
        int4 na = *(const int4*)(nbrp + hc*8);
        int4 nb = *(const int4*)(nbrp + hc*8 + 4);
        float idv = invd[hc];
        short8 bfr[K7];
        gather7(bfr, xb, hc, na, nb, quad);
        f32x4 acc0 = {0.f,0.f,0.f,0.f};
        f32x4 acc1 = {0.f,0.f,0.f,0.f};
        #pragma unroll
        for (int kk = 0; kk < K7; kk++){
            acc0 = __builtin_amdgcn_mfma_f32_16x16x32_bf16(af[0][kk], bfr[kk], acc0, 0, 0, 0);
            acc1 = __builtin_amdgcn_mfma_f32_16x16x32_bf16(af[1][kk], bfr[kk], acc1, 0, 0, 0);
        }
        uint32_t w_[4];
        #pragma unroll
        for (int p = 0; p < 2; p++){
            f32x4 a = p ? acc1 : acc0;
            w_[p*2]   = (uint32_t)f32_to_bf16(a[0]*idv) | ((uint32_t)f32_to_bf16(a[1]*idv) << 16);
            w_[p*2+1] = (uint32_t)f32_to_bf16(a[2]*idv) | ((uint32_t)f32_to_bf16(a[3]*idv) << 16);
        }
        uint4 pk; pk.x = w_[0]; pk.y = w_[1]; pk.z = w_[2]; pk.w = w_[3];
        held[it*256 + t] = pk;            // 16B stride across lanes: conflict-free
    }

    // ---- Phase B1: BN stat partials from parked values ----
    float sacc[8]  = {0,0,0,0,0,0,0,0};
    float sacc2[8] = {0,0,0,0,0,0,0,0};
    #pragma unroll
    for (int it = 0; it < 8; it++){
        uint4 pk = held[it*256 + t];
        uint32_t w_[4] = {pk.x, pk.y, pk.z, pk.w};
        #pragma unroll
        for (int i = 0; i < 8; i++){
            float v = bf16_to_f32((unsigned short)((w_[i>>1] >> ((i&1)*16)) & 0xFFFF));
            sacc[i]  += v;
            sacc2[i] += v*v;
        }
    }
    #pragma unroll
    for (int bit = 1; bit < 16; bit <<= 1){
        #pragma unroll
        for (int i = 0; i < 8; i++){
            sacc[i]  += __shfl_xor(sacc[i],  bit);
            sacc2[i] += __shfl_xor(sacc2[i], bit);
        }
    }
    if (n == 0){
        int slot = blockIdx.x & 63;
        #pragma unroll
        for (int p = 0; p < 2; p++)
            #pragma unroll
            for (int r = 0; r < 4; r++){
                int o = p*16 + quad*4 + r;
                atomicAdd(&ostatp[slot*64 + o],      sacc[p*4 + r]);
                atomicAdd(&ostatp[slot*64 + 32 + o], sacc2[p*4 + r]);
            }
    }

    // ---- Grid barrier (all 1024 blocks co-resident) ----
    __syncthreads();
    if (t == 0){
        __threadfence();
        __hip_atomic_store(&bar[blockIdx.x], 1, __ATOMIC_RELEASE, __HIP_MEMORY_SCOPE_AGENT);
    }
    {
        const int* s0 = bar + t*4;        // 256 threads x 4 slots = 1024
        long tries = 0;
        for (;;){
            int c = __hip_atomic_load(s0+0, __ATOMIC_ACQUIRE, __HIP_MEMORY_SCOPE_AGENT)
                  + __hip_atomic_load(s0+1, __ATOMIC_ACQUIRE, __HIP_MEMORY_SCOPE_AGENT)
                  + __hip_atomic_load(s0+2, __ATOMIC_ACQUIRE, __HIP_MEMORY_SCOPE_AGENT)
                  + __hip_atomic_load(s0+3, __ATOMIC_ACQUIRE, __HIP_MEMORY_SCOPE_AGENT);
            if (c == 4) break;
            if (++tries > (1L<<24)) break;          // bounded: fail visibly, never hang
            __builtin_amdgcn_s_sleep(8);
        }
        __threadfence();
        __syncthreads();
    }

    // ---- Phase B2: redundant reduction -> BN coefficients ----
    {
        int a = t & 63, g = t >> 6;
        float s = 0.0f;
        #pragma unroll
        for (int jj = 0; jj < 16; jj++)
            s += __hip_atomic_load(&ostatp[(g*16 + jj)*64 + a],
                                   __ATOMIC_RELAXED, __HIP_MEMORY_SCOPE_AGENT);
        part[g][a] = s;
        __syncthreads();
        if (t < 64) part[0][t] = part[0][t] + part[1][t] + part[2][t] + part[3][t];
        __syncthreads();
        if (t < 32){
            float mean = part[0][t]      * (1.0f/(float)NBH);
            float var  = part[0][32 + t] * (1.0f/(float)NBH) - mean*mean;
            float sc = gamma[t] * rsqrtf(var + 1e-5f);
            scsh[t] = sc;
            scsh[32 + t] = beta[t] - mean*sc;
        }
        __syncthreads();
    }
    float sA[8], sB[8];
    #pragma unroll
    for (int p = 0; p < 2; p++)
        #pragma unroll
        for (int r = 0; r < 4; r++){
            int o = p*16 + quad*4 + r;
            sA[p*4 + r] = scsh[o];
            sB[p*4 + r] = scsh[32 + o];
        }

    // ---- Phase B3: unpark, apply BN, write out ----
    #pragma unroll 2
    for (int it = 0; it < 8; it++){
        int hc = hbase + it*16 + n;
        uint4 pk = held[it*256 + t];
        uint32_t w_[4] = {pk.x, pk.y, pk.z, pk.w};
        #pragma unroll
        for (int p = 0; p < 2; p++)
            #pragma unroll
            for (int r = 0; r < 4; r++){
                int i = p*4 + r;
                float v = bf16_to_f32((unsigned short)((w_[i>>1] >> ((i&1)*16)) & 0xFFFF));
                int o = p*16 + quad*4 + r;
                out[((size_t)(b*COUT + o))*HN + hc] = v*sA[i] + sB[i];
            }
    }
}

// ---------------------------------------------------------------------------
extern "C" void kernel_launch(void* const* d_in, const int* in_sizes, int n_in,
                              void* d_out, int out_size, void* d_ws, size_t ws_size,
                              hipStream_t stream) {
    const float* x      = (const float*)d_in[0];
    const float* weight = (const float*)d_in[1];
    // d_in[2] = bias — exactly cancelled by BatchNorm mean subtraction
    const float* gamma  = (const float*)d_in[3];
    const float* beta   = (const float*)d_in[4];
    const int*   nbr    = (const int*)d_in[5];   // int64 in reference -> int32 from harness
    // d_in[6] = groups (==1), ignored

    char* ws = (char*)d_ws;
    unsigned short* xt    = (unsigned short*)(ws + WS_XT);
    unsigned short* wt    = (unsigned short*)(ws + WS_WT);
    int*            nbrp  = (int*)(ws + WS_NBR);
    float*          invd  = (float*)(ws + WS_INVD);
    float*          ostatp= (float*)(ws + WS_OSTP);
    int*            bar   = (int*)(ws + WS_BAR);
    float*          out   = (float*)d_out;

    kinit <<<17,   256, 0, stream>>>(nbr, weight, nbrp, invd, wt, ostatp, bar);
    ktrans<<<2048, 256, 0, stream>>>(x, xt);
    kfused<<<1024, 256, 0, stream>>>(xt, wt, nbrp, invd, gamma, beta, out, ostatp, bar);
}